// Round 9
// baseline (378.118 us; speedup 1.0000x reference)
//
#include <hip/hip_runtime.h>
#include <hip/hip_fp16.h>
#include <math.h>

#define N_NODES 50000
#define E_EDGES 1600000
#define G_GRAPHS 512
#define IN_DIM 64
#define EMBED 128
#define HD 128
#define NHEAD 4
#define D1 128
#define D2 64
#define D3 16
#define NEG_SLOPE 0.2f
#define NB ((N_NODES + 127) >> 7)                       // 391 coarse buckets (128 nodes each)
#define PT_TILE 4096
#define PT_BLOCKS ((E_EDGES + PT_TILE - 1) / PT_TILE)   // 391
#define FB_CAP 8192
#define NPW 32                                          // nodes per wave in k6agg

typedef float vfloat4 __attribute__((ext_vector_type(4)));
typedef unsigned short ushort_t;

static __device__ __forceinline__ float leaky(float x) { return x > 0.f ? x : NEG_SLOPE * x; }

// K0+HG merged: blocks [0,PT_BLOCKS) do the coarse dst-histogram; the rest compute
// Wcomb = W0 @ Wfc and bcomb = b0 @ Wfc.
__global__ void __launch_bounds__(256) k0hg(const int* __restrict__ dst, int* __restrict__ ghist,
                                            const float* __restrict__ W0, const float* __restrict__ b0,
                                            const float* __restrict__ Wfc, float* __restrict__ Wc,
                                            float* __restrict__ bc) {
    __shared__ int lh[NB];
    const int t = threadIdx.x;
    if (blockIdx.x < PT_BLOCKS) {
        for (int i = t; i < NB; i += 256) lh[i] = 0;
        __syncthreads();
        const long e0 = (long)blockIdx.x * PT_TILE;
#pragma unroll
        for (int k = 0; k < PT_TILE / 256; ++k) {
            long e = e0 + t + k * 256;
            if (e < E_EDGES) atomicAdd(&lh[dst[e] >> 7], 1);
        }
        __syncthreads();
        for (int i = t; i < NB; i += 256) {
            int v = lh[i];
            if (v) atomicAdd(&ghist[i], v);
        }
    } else {
        int tid = (int)(blockIdx.x - PT_BLOCKS) * 256 + t;
        if (tid < IN_DIM * HD) {
            int i = tid >> 7, j = tid & 127;
            float acc = 0.f;
            for (int k = 0; k < EMBED; ++k) acc += W0[i * EMBED + k] * Wfc[k * HD + j];
            Wc[tid] = acc;
        } else if (tid < IN_DIM * HD + HD) {
            int j = tid - IN_DIM * HD;
            float acc = 0.f;
            for (int k = 0; k < EMBED; ++k) acc += b0[k] * Wfc[k * HD + j];
            bc[j] = acc;
        }
    }
}

// K1: feat_s (slice-major fp16) = feature @ Wc + bc; el/er epilogue from LDS tile.
// feat_s[s][n][16ch], s = channel/16 -> 1.6 MB per slice.
__global__ void __launch_bounds__(256) k1_gemm(const float* __restrict__ A,
                                               const float* __restrict__ W,
                                               const float* __restrict__ b,
                                               const float* __restrict__ attn_l,
                                               const float* __restrict__ attn_r,
                                               __half* __restrict__ feat_s,
                                               float* __restrict__ el,
                                               float* __restrict__ er) {
    __shared__ float Ws[IN_DIM * HD];   // 32 KB
    __shared__ float As[32][65];        // 8.3 KB
    __shared__ float fs[32][132];       // 16.9 KB
    const int t = threadIdx.x;
    const int c = t & 127, rr = t >> 7;
    const int row0 = blockIdx.x * 32;
    for (int i = t; i < IN_DIM * HD; i += 256) Ws[i] = W[i];
    for (int i = t; i < 32 * IN_DIM; i += 256) {
        int r = i >> 6, k = i & 63;
        int gr = row0 + r;
        As[r][k] = (gr < N_NODES) ? A[(size_t)gr * IN_DIM + k] : 0.f;
    }
    __syncthreads();
    float acc[16];
#pragma unroll
    for (int i = 0; i < 16; ++i) acc[i] = 0.f;
    for (int k = 0; k < IN_DIM; ++k) {
        float w = Ws[k * HD + c];
#pragma unroll
        for (int i = 0; i < 16; ++i) acc[i] += As[rr * 16 + i][k] * w;
    }
    const float bb = b[c];
#pragma unroll
    for (int i = 0; i < 16; ++i) fs[rr * 16 + i][c] = acc[i] + bb;
    __syncthreads();
    // feat_s epilogue: unit = (row, slice); 16 ch -> 8 half2 -> two 16B stores
    {
        const int row = t >> 3, s = t & 7;
        const int gr = row0 + row;
        if (gr < N_NODES) {
            __half2 hbuf[8];
#pragma unroll
            for (int k = 0; k < 8; ++k) {
                float2 f2 = make_float2(fs[row][s * 16 + 2 * k], fs[row][s * 16 + 2 * k + 1]);
                hbuf[k] = __float22half2_rn(f2);
            }
            __half* dstp = feat_s + ((size_t)s * N_NODES + gr) * 16;
            *(vfloat4*)dstp = *(vfloat4*)&hbuf[0];
            *(vfloat4*)(dstp + 8) = *(vfloat4*)&hbuf[4];
        }
    }
    // el/er epilogue: 8 threads per row, 16 channels each; pairs combine to one head.
    {
        const int r = t >> 3, q = t & 7, c0 = q * 16, h = q >> 1;
        float pl = 0.f, pr = 0.f;
#pragma unroll
        for (int k = 0; k < 16; ++k) {
            float f = fs[r][c0 + k];
            pl += f * attn_l[c0 + k];
            pr += f * attn_r[c0 + k];
        }
        pl += __shfl_xor(pl, 1);
        pr += __shfl_xor(pr, 1);
        if ((t & 1) == 0) {
            int n = row0 + r;
            if (n < N_NODES) {
                el[n * 4 + h] = pl;
                er[n * 4 + h] = pr;
            }
        }
    }
}

// SC: exclusive scan of NB coarse counts -> coarse_start + cursor (one wave)
__global__ void __launch_bounds__(64) sc_scan(const int* __restrict__ ghist,
                                              int* __restrict__ coarse_start,
                                              int* __restrict__ cursorp) {
    const int lane = threadIdx.x;
    int run = 0;
    for (int c = 0; c < (NB + 63) / 64; ++c) {
        int i = c * 64 + lane;
        int v = (i < NB) ? ghist[i] : 0;
        int incl = v;
#pragma unroll
        for (int off = 1; off < 64; off <<= 1) {
            int o = __shfl_up(incl, off, 64);
            if (lane >= off) incl += o;
        }
        if (i < NB) {
            coarse_start[i] = run + incl - v;
            cursorp[i] = run + incl - v;
        }
        run += __shfl(incl, 63, 64);
    }
    if (lane == 0) coarse_start[NB] = E_EDGES;
}

// PT: partition edges into coarse buckets; packed records (dst<<16)|src; per-wave hist.
__global__ void __launch_bounds__(256) pt_partition(const int* __restrict__ src,
                                                    const int* __restrict__ dst,
                                                    int* __restrict__ cursorp,
                                                    unsigned int* __restrict__ part) {
    __shared__ int hist[4][NB];
    __shared__ int tot[NB], offs[NB], base_s[NB];
    __shared__ int lcur[4][NB];
    __shared__ unsigned int stage[PT_TILE];  // 16 KB
    const int t = threadIdx.x, lane = t & 63, wid = t >> 6;
    const long e0 = (long)blockIdx.x * PT_TILE;
    const int cnt = (int)min((long)PT_TILE, (long)E_EDGES - e0);
    for (int i = t; i < NB; i += 256) {
        hist[0][i] = 0; hist[1][i] = 0; hist[2][i] = 0; hist[3][i] = 0;
    }
    __syncthreads();
    unsigned int v[PT_TILE / 256];
#pragma unroll
    for (int k = 0; k < PT_TILE / 256; ++k) {
        int i = t + k * 256;
        if (i < cnt) {
            int d = dst[e0 + i];
            v[k] = ((unsigned int)d << 16) | (unsigned int)src[e0 + i];
            atomicAdd(&hist[wid][d >> 7], 1);
        } else v[k] = 0xFFFFFFFFu;
    }
    __syncthreads();
    for (int i = t; i < NB; i += 256) {
        int h0 = hist[0][i], h1 = hist[1][i], h2 = hist[2][i], h3 = hist[3][i];
        hist[0][i] = 0; hist[1][i] = h0; hist[2][i] = h0 + h1; hist[3][i] = h0 + h1 + h2;
        tot[i] = h0 + h1 + h2 + h3;
    }
    __syncthreads();
    if (wid == 0) {
        int run = 0;
        for (int c = 0; c < (NB + 63) / 64; ++c) {
            int i = c * 64 + lane;
            int vv = (i < NB) ? tot[i] : 0;
            int incl = vv;
#pragma unroll
            for (int off = 1; off < 64; off <<= 1) {
                int o = __shfl_up(incl, off, 64);
                if (lane >= off) incl += o;
            }
            if (i < NB) offs[i] = run + incl - vv;
            run += __shfl(incl, 63, 64);
        }
    }
    __syncthreads();
    for (int i = t; i < NB; i += 256) {
        int tt = tot[i];
        base_s[i] = tt ? atomicAdd(&cursorp[i], tt) : 0;
        int ob = offs[i];
        lcur[0][i] = ob + hist[0][i];
        lcur[1][i] = ob + hist[1][i];
        lcur[2][i] = ob + hist[2][i];
        lcur[3][i] = ob + hist[3][i];
    }
    __syncthreads();
#pragma unroll
    for (int k = 0; k < PT_TILE / 256; ++k) {
        if (v[k] != 0xFFFFFFFFu) {
            int b = v[k] >> 23;
            int pos = atomicAdd(&lcur[wid][b], 1);
            stage[pos] = v[k];
        }
    }
    __syncthreads();
    for (int i = t; i < cnt; i += 256) {
        unsigned int p = stage[i];
        int b = p >> 23;
        part[base_s[b] + (i - offs[b])] = p & 0x7FFFFFu;  // (dst&127)<<16 | src
    }
}

// FB: per-bucket fine fill -> rowstart + coalesced ushort csr_src
__global__ void __launch_bounds__(256) fb_fill(const unsigned int* __restrict__ part,
                                               const int* __restrict__ coarse_start,
                                               int* __restrict__ rowstart,
                                               ushort_t* __restrict__ csr_src) {
    const int b = blockIdx.x, t = threadIdx.x, lane = t & 63, wid = t >> 6;
    const int s0 = coarse_start[b], s1 = coarse_start[b + 1];
    const int cnt = s1 - s0;
    __shared__ int degl[4][128], totl[128], offl[128], curl[4][128];
    __shared__ ushort_t lsrc[FB_CAP];  // 16 KB
    if (t < 128) { degl[0][t] = 0; degl[1][t] = 0; degl[2][t] = 0; degl[3][t] = 0; }
    __syncthreads();
    for (int i = t; i < cnt; i += 256) {
        unsigned int p = part[s0 + i];
        atomicAdd(&degl[wid][p >> 16], 1);
    }
    __syncthreads();
    if (t < 128) {
        int d0 = degl[0][t], d1 = degl[1][t], d2 = degl[2][t], d3 = degl[3][t];
        degl[0][t] = 0; degl[1][t] = d0; degl[2][t] = d0 + d1; degl[3][t] = d0 + d1 + d2;
        totl[t] = d0 + d1 + d2 + d3;
    }
    __syncthreads();
    if (wid == 0) {
        int run = 0;
        for (int c = 0; c < 2; ++c) {
            int i = c * 64 + lane;
            int vv = totl[i];
            int incl = vv;
#pragma unroll
            for (int off = 1; off < 64; off <<= 1) {
                int o = __shfl_up(incl, off, 64);
                if (lane >= off) incl += o;
            }
            offl[i] = run + incl - vv;
            run += __shfl(incl, 63, 64);
        }
    }
    __syncthreads();
    if (t < 128) {
        int ob = offl[t];
        curl[0][t] = ob + degl[0][t];
        curl[1][t] = ob + degl[1][t];
        curl[2][t] = ob + degl[2][t];
        curl[3][t] = ob + degl[3][t];
        int node = b * 128 + t;
        if (node < N_NODES) rowstart[node] = s0 + ob;
    }
    if (b == 0 && t == 0) rowstart[N_NODES] = E_EDGES;
    __syncthreads();
    if (cnt <= FB_CAP) {
        for (int i = t; i < cnt; i += 256) {
            unsigned int p = part[s0 + i];
            int pos = atomicAdd(&curl[wid][p >> 16], 1);
            lsrc[pos] = (ushort_t)(p & 0xFFFFu);
        }
        __syncthreads();
        for (int i = t; i < cnt; i += 256) csr_src[s0 + i] = lsrc[i];
    } else {
        for (int i = t; i < cnt; i += 256) {
            unsigned int p = part[s0 + i];
            int pos = atomicAdd(&curl[wid][p >> 16], 1);
            csr_src[s0 + pos] = (ushort_t)(p & 0xFFFFu);
        }
    }
}

// K6S: per-dst softmax denominators (no-max form). One wave per dst.
// Writes er_rd[n] = {er4, rd4} (32 B) consumed by k6agg and k6b.
__global__ void __launch_bounds__(256) k6s_stats(
    const ushort_t* __restrict__ csr_src, const int* __restrict__ rowstart,
    const float* __restrict__ el, const float* __restrict__ er,
    float* __restrict__ er_rd) {
    const int wid = threadIdx.x >> 6, lane = threadIdx.x & 63;
    const int n = blockIdx.x * 4 + wid;
    if (n >= N_NODES) return;
    const int start = rowstart[n], end = rowstart[n + 1];
    const float4 er4 = *(const float4*)(er + n * 4);
    float4 sm = make_float4(0.f, 0.f, 0.f, 0.f);
    for (int e = start + lane; e < end; e += 64) {
        int s = csr_src[e];
        const float4 elv = *(const float4*)(el + s * 4);
        sm.x += __expf(leaky(elv.x + er4.x));
        sm.y += __expf(leaky(elv.y + er4.y));
        sm.z += __expf(leaky(elv.z + er4.z));
        sm.w += __expf(leaky(elv.w + er4.w));
    }
#pragma unroll
    for (int off = 32; off; off >>= 1) {
        sm.x += __shfl_xor(sm.x, off);
        sm.y += __shfl_xor(sm.y, off);
        sm.z += __shfl_xor(sm.z, off);
        sm.w += __shfl_xor(sm.w, off);
    }
    if (lane == 0) {
        float4 rd;
        rd.x = sm.x > 0.f ? 1.f / sm.x : 0.f;
        rd.y = sm.y > 0.f ? 1.f / sm.y : 0.f;
        rd.z = sm.z > 0.f ? 1.f / sm.z : 0.f;
        rd.w = sm.w > 0.f ? 1.f / sm.w : 0.f;
        *(float4*)(er_rd + (size_t)n * 8) = er4;
        *(float4*)(er_rd + (size_t)n * 8 + 4) = rd;
    }
}

// K6AGG: slice-major aggregation. slice = blockIdx % 8 (round-robin XCD -> each XCD's
// working set = one 1.6 MB feat slice, L2-resident). One wave = NPW nodes for its slice.
__global__ void __launch_bounds__(256) k6agg(
    const ushort_t* __restrict__ csr_src, const int* __restrict__ rowstart,
    const float* __restrict__ el, const float* __restrict__ er_rd,
    const __half* __restrict__ feat_s, const float* __restrict__ gat_bias,
    float* __restrict__ hn) {
    __shared__ float s_av[4][64];
    __shared__ int s_src[4][64];
    const int wid = threadIdx.x >> 6, lane = threadIdx.x & 63;
    const int s = blockIdx.x & 7;
    const int g = blockIdx.x >> 3;
    const int h = s >> 1;
    const int c4 = lane & 3, e16 = lane >> 2;
    const __half* fslice = feat_s + (size_t)s * N_NODES * 16;
    const float4 bias = *(const float4*)(gat_bias + s * 16 + c4 * 4);
    const int n0 = (g * 4 + wid) * NPW;
    const int n1 = min(n0 + NPW, N_NODES);
    for (int n = n0; n < n1; ++n) {
        const int start = rowstart[n], end = rowstart[n + 1];
        const float erh = er_rd[(size_t)n * 8 + h];
        const float rdh = er_rd[(size_t)n * 8 + 4 + h];
        float4 acc = make_float4(0.f, 0.f, 0.f, 0.f);
        for (int cbase = start; cbase < end; cbase += 64) {
            const int m = min(64, end - cbase);
            float av = 0.f;
            int sv = 0;
            if (lane < m) {
                sv = csr_src[cbase + lane];
                av = __expf(leaky(el[sv * 4 + h] + erh)) * rdh;
            }
            s_av[wid][lane] = av;
            s_src[wid][lane] = sv;
            const int iters = (m + 15) >> 4;
            int idx = e16;
            for (int it = 0; it < iters; ++it, idx += 16) {
                const float a = s_av[wid][idx];      // 0 for pad lanes
                const int cs = s_src[wid][idx];
                const float2 raw = *(const float2*)(fslice + (size_t)cs * 16 + c4 * 4);
                const __half2* q = (const __half2*)&raw;
                const float2 p0 = __half22float2(q[0]);
                const float2 p1 = __half22float2(q[1]);
                acc.x += a * p0.x;
                acc.y += a * p0.y;
                acc.z += a * p1.x;
                acc.w += a * p1.y;
            }
        }
#pragma unroll
        for (int off = 4; off <= 32; off <<= 1) {
            acc.x += __shfl_xor(acc.x, off);
            acc.y += __shfl_xor(acc.y, off);
            acc.z += __shfl_xor(acc.z, off);
            acc.w += __shfl_xor(acc.w, off);
        }
        if (lane < 4) {
            *(float4*)(hn + (size_t)n * HD + s * 16 + c4 * 4) =
                make_float4(acc.x + bias.x, acc.y + bias.y, acc.z + bias.z, acc.w + bias.w);
        }
    }
}

// K6B: attention coefficients in edge order (2 gathers: el[s] + er_rd[d])
__global__ void __launch_bounds__(256) k6b_attn(
    const int* __restrict__ src, const int* __restrict__ dst,
    const float* __restrict__ el, const float* __restrict__ er_rd,
    float* __restrict__ a_out) {
    int e = blockIdx.x * 256 + threadIdx.x;
    if (e >= E_EDGES) return;
    const int s = src[e], d = dst[e];
    const float4 el4 = *(const float4*)(el + s * 4);
    const float4 er4 = *(const float4*)(er_rd + (size_t)d * 8);
    const float4 r4 = *(const float4*)(er_rd + (size_t)d * 8 + 4);
    vfloat4 a;
    a.x = __expf(leaky(el4.x + er4.x)) * r4.x;
    a.y = __expf(leaky(el4.y + er4.y)) * r4.y;
    a.z = __expf(leaky(el4.z + er4.z)) * r4.z;
    a.w = __expf(leaky(el4.w + er4.w)) * r4.w;
    __builtin_nontemporal_store(a, (vfloat4*)a_out + e);
}

// K7: deterministic f64 mean-pool + f64 MLP.
__global__ void __launch_bounds__(512) k7_pool_mlp(
    const float* __restrict__ hn, const int* __restrict__ graph_ids,
    const float* __restrict__ W1, const float* __restrict__ b1,
    const float* __restrict__ W2, const float* __restrict__ b2,
    const float* __restrict__ W3, const float* __restrict__ b3,
    float* __restrict__ out) {
    const int g = blockIdx.x, t = threadIdx.x;
    const int tt = t & 127, part = t >> 7;
    __shared__ int bounds[2];
    __shared__ double pool[4][128];
    __shared__ double x[128], y[128];
    if (t < 2) {
        const int target = g + t;
        int lo = 0, hi = N_NODES;
        while (lo < hi) {
            int mid = (lo + hi) >> 1;
            if (graph_ids[mid] < target) lo = mid + 1; else hi = mid;
        }
        bounds[t] = lo;
    }
    __syncthreads();
    const int lo = bounds[0], hi = bounds[1];
    double s = 0.0;
    for (int n = lo + part; n < hi; n += 4) s += (double)hn[(size_t)n * HD + tt];
    pool[part][tt] = s;
    __syncthreads();
    if (t < 128) {
        const double cnt = (double)(hi - lo);
        const double sum = pool[0][t] + pool[1][t] + pool[2][t] + pool[3][t];
        const double v = sum / fmax(cnt, 1.0);
        x[t] = v > 0.0 ? v : expm1(v);
    }
    __syncthreads();
    if (t < 128) {
        double acc = (double)b1[t];
        for (int k = 0; k < HD; ++k) acc += x[k] * (double)W1[k * D1 + t];
        y[t] = acc > 0.0 ? acc : expm1(acc);
    }
    __syncthreads();
    if (t < D2) {
        double a2 = (double)b2[t];
        for (int k = 0; k < D1; ++k) a2 += y[k] * (double)W2[k * D2 + t];
        x[t] = a2 > 0.0 ? a2 : expm1(a2);
    }
    __syncthreads();
    if (t < D3) {
        double a3 = (double)b3[t];
        for (int k = 0; k < D2; ++k) a3 += x[k] * (double)W3[k * D3 + t];
        out[g * D3 + t] = (float)a3;
    }
}

extern "C" void kernel_launch(void* const* d_in, const int* in_sizes, int n_in,
                              void* d_out, int out_size, void* d_ws, size_t ws_size,
                              hipStream_t stream) {
    const float* feature = (const float*)d_in[0];
    const int* src = (const int*)d_in[1];
    const int* dst = (const int*)d_in[2];
    const int* graph_ids = (const int*)d_in[3];
    const float* W0 = (const float*)d_in[4];
    const float* b0 = (const float*)d_in[5];
    const float* Wfc = (const float*)d_in[6];
    const float* attn_l = (const float*)d_in[7];
    const float* attn_r = (const float*)d_in[8];
    const float* gat_bias = (const float*)d_in[9];
    const float* W1 = (const float*)d_in[10];
    const float* b1 = (const float*)d_in[11];
    const float* W2 = (const float*)d_in[12];
    const float* b2 = (const float*)d_in[13];
    const float* W3 = (const float*)d_in[14];
    const float* b3 = (const float*)d_in[15];

    char* ws = (char*)d_ws;
    size_t off = 0;
    auto carve = [&](size_t bytes) -> void* {
        void* p = ws + off;
        off += (bytes + 255) & ~(size_t)255;
        return p;
    };
    int* ghist = (int*)carve((size_t)NB * 4);
    const size_t zero_span = off;
    int* coarse_start = (int*)carve((size_t)(NB + 1) * 4);
    int* cursorp = (int*)carve((size_t)NB * 4);
    float* Wc = (float*)carve((size_t)IN_DIM * HD * 4);
    float* bc = (float*)carve((size_t)HD * 4);
    __half* feat_s = (__half*)carve((size_t)N_NODES * HD * 2);
    float* el = (float*)carve((size_t)N_NODES * 4 * 4);
    float* er = (float*)carve((size_t)N_NODES * 4 * 4);
    float* er_rd = (float*)carve((size_t)N_NODES * 8 * 4);
    int* rowstart = (int*)carve((size_t)(N_NODES + 1) * 4);
    unsigned int* part = (unsigned int*)carve((size_t)E_EDGES * 4);
    ushort_t* csr_src = (ushort_t*)carve((size_t)E_EDGES * 2);

    float* out = (float*)d_out;
    // atten region of d_out doubles as hn scratch: k6agg writes hn, k7 reads it,
    // THEN k6b overwrites the region with the final attention output.
    float* hn = out + G_GRAPHS * D3;
    float* a_out = hn;

    (void)hipMemsetAsync(d_ws, 0, zero_span, stream);
    k0hg<<<PT_BLOCKS + 33, 256, 0, stream>>>(dst, ghist, W0, b0, Wfc, Wc, bc);
    k1_gemm<<<(N_NODES + 31) / 32, 256, 0, stream>>>(feature, Wc, bc, attn_l, attn_r,
                                                     feat_s, el, er);
    sc_scan<<<1, 64, 0, stream>>>(ghist, coarse_start, cursorp);
    pt_partition<<<PT_BLOCKS, 256, 0, stream>>>(src, dst, cursorp, part);
    fb_fill<<<NB, 256, 0, stream>>>(part, coarse_start, rowstart, csr_src);
    k6s_stats<<<(N_NODES + 3) / 4, 256, 0, stream>>>(csr_src, rowstart, el, er, er_rd);
    {
        const int ngroups = (N_NODES + 4 * NPW - 1) / (4 * NPW);
        k6agg<<<ngroups * 8, 256, 0, stream>>>(csr_src, rowstart, el, er_rd, feat_s,
                                               gat_bias, hn);
    }
    k7_pool_mlp<<<G_GRAPHS, 512, 0, stream>>>(hn, graph_ids, W1, b1, W2, b2, W3, b3, out);
    k6b_attn<<<(E_EDGES + 255) / 256, 256, 0, stream>>>(src, dst, el, er_rd, a_out);
}

// Round 10
// 309.939 us; speedup vs baseline: 1.2200x; 1.2200x over previous
//
#include <hip/hip_runtime.h>
#include <hip/hip_fp16.h>
#include <math.h>

#define N_NODES 50000
#define E_EDGES 1600000
#define G_GRAPHS 512
#define IN_DIM 64
#define EMBED 128
#define HD 128
#define NHEAD 4
#define D1 128
#define D2 64
#define D3 16
#define NEG_SLOPE 0.2f
#define BSH 6                                           // bucket shift: 64 nodes per bucket
#define NB ((N_NODES + 63) >> BSH)                      // 782 coarse buckets
#define PT_TILE 2048
#define PT_BLOCKS ((E_EDGES + PT_TILE - 1) / PT_TILE)   // 782
#define FB_CAP 4096

typedef float vfloat4 __attribute__((ext_vector_type(4)));
typedef unsigned short ushort_t;

static __device__ __forceinline__ float leaky(float x) { return x > 0.f ? x : NEG_SLOPE * x; }
static __device__ __forceinline__ float compf(float4 v, int i) {
    return i == 0 ? v.x : (i == 1 ? v.y : (i == 2 ? v.z : v.w));
}

// K0+HG merged: blocks [0,PT_BLOCKS) do the coarse dst-histogram; the rest compute
// Wcomb = W0 @ Wfc and bcomb = b0 @ Wfc.
__global__ void __launch_bounds__(256) k0hg(const int* __restrict__ dst, int* __restrict__ ghist,
                                            const float* __restrict__ W0, const float* __restrict__ b0,
                                            const float* __restrict__ Wfc, float* __restrict__ Wc,
                                            float* __restrict__ bc) {
    __shared__ int lh[NB];
    const int t = threadIdx.x;
    if (blockIdx.x < PT_BLOCKS) {
        for (int i = t; i < NB; i += 256) lh[i] = 0;
        __syncthreads();
        const long e0 = (long)blockIdx.x * PT_TILE;
#pragma unroll
        for (int k = 0; k < PT_TILE / 256; ++k) {
            long e = e0 + t + k * 256;
            if (e < E_EDGES) atomicAdd(&lh[dst[e] >> BSH], 1);
        }
        __syncthreads();
        for (int i = t; i < NB; i += 256) {
            int v = lh[i];
            if (v) atomicAdd(&ghist[i], v);
        }
    } else {
        int tid = (int)(blockIdx.x - PT_BLOCKS) * 256 + t;
        if (tid < IN_DIM * HD) {
            int i = tid >> 7, j = tid & 127;
            float acc = 0.f;
            for (int k = 0; k < EMBED; ++k) acc += W0[i * EMBED + k] * Wfc[k * HD + j];
            Wc[tid] = acc;
        } else if (tid < IN_DIM * HD + HD) {
            int j = tid - IN_DIM * HD;
            float acc = 0.f;
            for (int k = 0; k < EMBED; ++k) acc += b0[k] * Wfc[k * HD + j];
            bc[j] = acc;
        }
    }
}

// K1 (fused): feat = fp16(feature @ Wc + bc) row-major; el/er epilogue from LDS tile.
__global__ void __launch_bounds__(256) k1_gemm(const float* __restrict__ A,
                                               const float* __restrict__ W,
                                               const float* __restrict__ b,
                                               const float* __restrict__ attn_l,
                                               const float* __restrict__ attn_r,
                                               __half* __restrict__ out,
                                               float* __restrict__ el,
                                               float* __restrict__ er) {
    __shared__ float Ws[IN_DIM * HD];   // 32 KB
    __shared__ float As[32][65];        // 8.3 KB
    __shared__ float fs[32][132];       // 16.9 KB
    const int t = threadIdx.x;
    const int c = t & 127, rr = t >> 7;
    const int row0 = blockIdx.x * 32;
    for (int i = t; i < IN_DIM * HD; i += 256) Ws[i] = W[i];
    for (int i = t; i < 32 * IN_DIM; i += 256) {
        int r = i >> 6, k = i & 63;
        int gr = row0 + r;
        As[r][k] = (gr < N_NODES) ? A[(size_t)gr * IN_DIM + k] : 0.f;
    }
    __syncthreads();
    float acc[16];
#pragma unroll
    for (int i = 0; i < 16; ++i) acc[i] = 0.f;
    for (int k = 0; k < IN_DIM; ++k) {
        float w = Ws[k * HD + c];
#pragma unroll
        for (int i = 0; i < 16; ++i) acc[i] += As[rr * 16 + i][k] * w;
    }
    const float bb = b[c];
#pragma unroll
    for (int i = 0; i < 16; ++i) {
        int gr = row0 + rr * 16 + i;
        float fv = acc[i] + bb;
        fs[rr * 16 + i][c] = fv;
        if (gr < N_NODES) out[(size_t)gr * HD + c] = __float2half(fv);
    }
    __syncthreads();
    const int r = t >> 3, q = t & 7, c0 = q * 16, h = q >> 1;
    float pl = 0.f, pr = 0.f;
#pragma unroll
    for (int k = 0; k < 16; ++k) {
        float f = fs[r][c0 + k];
        pl += f * attn_l[c0 + k];
        pr += f * attn_r[c0 + k];
    }
    pl += __shfl_xor(pl, 1);
    pr += __shfl_xor(pr, 1);
    if ((t & 1) == 0) {
        int n = row0 + r;
        if (n < N_NODES) {
            el[n * 4 + h] = pl;
            er[n * 4 + h] = pr;
        }
    }
}

// SC: exclusive scan of NB coarse counts -> coarse_start + cursor (one wave)
__global__ void __launch_bounds__(64) sc_scan(const int* __restrict__ ghist,
                                              int* __restrict__ coarse_start,
                                              int* __restrict__ cursorp) {
    const int lane = threadIdx.x;
    int run = 0;
    for (int c = 0; c < (NB + 63) / 64; ++c) {
        int i = c * 64 + lane;
        int v = (i < NB) ? ghist[i] : 0;
        int incl = v;
#pragma unroll
        for (int off = 1; off < 64; off <<= 1) {
            int o = __shfl_up(incl, off, 64);
            if (lane >= off) incl += o;
        }
        if (i < NB) {
            coarse_start[i] = run + incl - v;
            cursorp[i] = run + incl - v;
        }
        run += __shfl(incl, 63, 64);
    }
    if (lane == 0) coarse_start[NB] = E_EDGES;
}

// PT: partition edges into 782 coarse buckets (64 nodes each); packed records
// (dst<<16)|src; per-wave hist. 782 blocks x 2048 edges -> ~3 blocks/CU.
__global__ void __launch_bounds__(256) pt_partition(const int* __restrict__ src,
                                                    const int* __restrict__ dst,
                                                    int* __restrict__ cursorp,
                                                    unsigned int* __restrict__ part) {
    __shared__ int hist[4][NB];              // becomes per-wave exclusive prefix
    __shared__ int tot[NB], offs[NB], base_s[NB];
    __shared__ int lcur[4][NB];
    __shared__ unsigned int stage[PT_TILE];  // 8 KB
    const int t = threadIdx.x, lane = t & 63, wid = t >> 6;
    const long e0 = (long)blockIdx.x * PT_TILE;
    const int cnt = (int)min((long)PT_TILE, (long)E_EDGES - e0);
    for (int i = t; i < NB; i += 256) {
        hist[0][i] = 0; hist[1][i] = 0; hist[2][i] = 0; hist[3][i] = 0;
    }
    __syncthreads();
    unsigned int v[PT_TILE / 256];
#pragma unroll
    for (int k = 0; k < PT_TILE / 256; ++k) {
        int i = t + k * 256;
        if (i < cnt) {
            int d = dst[e0 + i];
            v[k] = ((unsigned int)d << 16) | (unsigned int)src[e0 + i];
            atomicAdd(&hist[wid][d >> BSH], 1);
        } else v[k] = 0xFFFFFFFFu;
    }
    __syncthreads();
    for (int i = t; i < NB; i += 256) {
        int h0 = hist[0][i], h1 = hist[1][i], h2 = hist[2][i], h3 = hist[3][i];
        hist[0][i] = 0; hist[1][i] = h0; hist[2][i] = h0 + h1; hist[3][i] = h0 + h1 + h2;
        tot[i] = h0 + h1 + h2 + h3;
    }
    __syncthreads();
    if (wid == 0) {
        int run = 0;
        for (int c = 0; c < (NB + 63) / 64; ++c) {
            int i = c * 64 + lane;
            int vv = (i < NB) ? tot[i] : 0;
            int incl = vv;
#pragma unroll
            for (int off = 1; off < 64; off <<= 1) {
                int o = __shfl_up(incl, off, 64);
                if (lane >= off) incl += o;
            }
            if (i < NB) offs[i] = run + incl - vv;
            run += __shfl(incl, 63, 64);
        }
    }
    __syncthreads();
    for (int i = t; i < NB; i += 256) {
        int tt = tot[i];
        base_s[i] = tt ? atomicAdd(&cursorp[i], tt) : 0;
        int ob = offs[i];
        lcur[0][i] = ob + hist[0][i];
        lcur[1][i] = ob + hist[1][i];
        lcur[2][i] = ob + hist[2][i];
        lcur[3][i] = ob + hist[3][i];
    }
    __syncthreads();
#pragma unroll
    for (int k = 0; k < PT_TILE / 256; ++k) {
        if (v[k] != 0xFFFFFFFFu) {
            int b = v[k] >> (16 + BSH);
            int pos = atomicAdd(&lcur[wid][b], 1);
            stage[pos] = v[k];
        }
    }
    __syncthreads();
    for (int i = t; i < cnt; i += 256) {
        unsigned int p = stage[i];
        int b = p >> (16 + BSH);
        part[base_s[b] + (i - offs[b])] = p & 0x3FFFFFu;  // (dst&63)<<16 | src
    }
}

// FB: per-bucket fine fill (64 nodes) -> rowstart + coalesced ushort csr_src
__global__ void __launch_bounds__(256) fb_fill(const unsigned int* __restrict__ part,
                                               const int* __restrict__ coarse_start,
                                               int* __restrict__ rowstart,
                                               ushort_t* __restrict__ csr_src) {
    const int b = blockIdx.x, t = threadIdx.x, lane = t & 63, wid = t >> 6;
    const int s0 = coarse_start[b], s1 = coarse_start[b + 1];
    const int cnt = s1 - s0;
    __shared__ int degl[4][64], offl[64], curl[4][64];
    __shared__ ushort_t lsrc[FB_CAP];  // 8 KB
    if (t < 64) { degl[0][t] = 0; degl[1][t] = 0; degl[2][t] = 0; degl[3][t] = 0; }
    __syncthreads();
    for (int i = t; i < cnt; i += 256) {
        unsigned int p = part[s0 + i];
        atomicAdd(&degl[wid][p >> 16], 1);
    }
    __syncthreads();
    if (wid == 0) {
        int d0 = degl[0][lane], d1 = degl[1][lane], d2 = degl[2][lane], d3 = degl[3][lane];
        int tot = d0 + d1 + d2 + d3;
        int incl = tot;
#pragma unroll
        for (int off = 1; off < 64; off <<= 1) {
            int o = __shfl_up(incl, off, 64);
            if (lane >= off) incl += o;
        }
        int ob = incl - tot;
        offl[lane] = ob;
        degl[0][lane] = 0;
        degl[1][lane] = d0;
        degl[2][lane] = d0 + d1;
        degl[3][lane] = d0 + d1 + d2;
    }
    __syncthreads();
    if (t < 64) {
        int ob = offl[t];
        curl[0][t] = ob + degl[0][t];
        curl[1][t] = ob + degl[1][t];
        curl[2][t] = ob + degl[2][t];
        curl[3][t] = ob + degl[3][t];
        int node = (b << BSH) + t;
        if (node < N_NODES) rowstart[node] = s0 + ob;
    }
    if (b == 0 && t == 0) rowstart[N_NODES] = E_EDGES;
    __syncthreads();
    if (cnt <= FB_CAP) {
        for (int i = t; i < cnt; i += 256) {
            unsigned int p = part[s0 + i];
            int pos = atomicAdd(&curl[wid][p >> 16], 1);
            lsrc[pos] = (ushort_t)(p & 0xFFFFu);
        }
        __syncthreads();
        for (int i = t; i < cnt; i += 256) csr_src[s0 + i] = lsrc[i];
    } else {
        for (int i = t; i < cnt; i += 256) {
            unsigned int p = part[s0 + i];
            int pos = atomicAdd(&curl[wid][p >> 16], 1);
            csr_src[s0 + pos] = (ushort_t)(p & 0xFFFFu);
        }
    }
}

// K6: per-dst softmax (no-max form) + aggregation, fused. One wave per dst.
// Pass 1 stashes per-edge av[4]/src in LDS; writes er_rd = {er4, rd4} for k6b.
__global__ void __launch_bounds__(256) k6_aggregate(
    const ushort_t* __restrict__ csr_src, const int* __restrict__ rowstart,
    const float* __restrict__ el, const float* __restrict__ er,
    const __half* __restrict__ feat, const float* __restrict__ gat_bias,
    float* __restrict__ er_rd, float* __restrict__ hn) {
    __shared__ float s_av[4][64][4];  // [wave][edge][head], 4 KB
    __shared__ int s_src[4][64];      // 1 KB
    const int wid = threadIdx.x >> 6;
    const int lane = threadIdx.x & 63;
    const int n = blockIdx.x * 4 + wid;
    if (n >= N_NODES) return;
    const int start = rowstart[n];
    const int end = rowstart[n + 1];
    const int deg = end - start;
    const float4 er4 = *(const float4*)(er + n * 4);

    // ---- pass 1: exp + sum (no max needed: |e| small so exp is safe) ----
    int esrc = 0;
    float4 ex = make_float4(0.f, 0.f, 0.f, 0.f);
    const bool valid = lane < deg;
    if (valid) {
        esrc = csr_src[start + lane];
        const float4 elv = *(const float4*)(el + esrc * 4);
        ex.x = __expf(leaky(elv.x + er4.x));
        ex.y = __expf(leaky(elv.y + er4.y));
        ex.z = __expf(leaky(elv.z + er4.z));
        ex.w = __expf(leaky(elv.w + er4.w));
    }
    float4 sm = ex;
    for (int e = start + lane + 64; e < end; e += 64) {  // deg>64: essentially never
        int s = csr_src[e];
        const float4 elv = *(const float4*)(el + s * 4);
        sm.x += __expf(leaky(elv.x + er4.x));
        sm.y += __expf(leaky(elv.y + er4.y));
        sm.z += __expf(leaky(elv.z + er4.z));
        sm.w += __expf(leaky(elv.w + er4.w));
    }
#pragma unroll
    for (int off = 32; off; off >>= 1) {
        sm.x += __shfl_xor(sm.x, off);
        sm.y += __shfl_xor(sm.y, off);
        sm.z += __shfl_xor(sm.z, off);
        sm.w += __shfl_xor(sm.w, off);
    }
    float4 rd;
    rd.x = sm.x > 0.f ? 1.f / sm.x : 0.f;
    rd.y = sm.y > 0.f ? 1.f / sm.y : 0.f;
    rd.z = sm.z > 0.f ? 1.f / sm.z : 0.f;
    rd.w = sm.w > 0.f ? 1.f / sm.w : 0.f;
    if (lane == 0) {
        *(float4*)(er_rd + (size_t)n * 8) = er4;
        *(float4*)(er_rd + (size_t)n * 8 + 4) = rd;
    }
    vfloat4 av4;
    av4.x = ex.x * rd.x;
    av4.y = ex.y * rd.y;
    av4.z = ex.z * rd.z;
    av4.w = ex.w * rd.w;
    s_src[wid][lane] = valid ? esrc : 0;
    *(vfloat4*)(&s_av[wid][lane][0]) = av4;

    // ---- pass 2: 16 lanes per edge (16B fp16 each = 8 channels, one head per lane) ----
    const int g4 = lane >> 4, gl = lane & 15;
    const int h = gl >> 2;
    float4 a0 = make_float4(0.f, 0.f, 0.f, 0.f);
    float4 a1 = make_float4(0.f, 0.f, 0.f, 0.f);

    if (deg <= 64) {
        const int iters = (deg + 3) >> 2;
        int idx = g4;
        for (int it = 0; it < iters; ++it, idx += 4) {
            const float av = s_av[wid][idx][h];
            const unsigned int cs = (unsigned int)s_src[wid][idx];
            const float4 raw = *(const float4*)(feat + cs * HD + gl * 8);
            const __half2* hp2 = (const __half2*)&raw;
            const float2 p0 = __half22float2(hp2[0]);
            const float2 p1 = __half22float2(hp2[1]);
            const float2 p2 = __half22float2(hp2[2]);
            const float2 p3 = __half22float2(hp2[3]);
            a0.x += av * p0.x; a0.y += av * p0.y;
            a0.z += av * p1.x; a0.w += av * p1.y;
            a1.x += av * p2.x; a1.y += av * p2.y;
            a1.z += av * p3.x; a1.w += av * p3.y;
        }
    } else {
        const float rh = compf(rd, h);
        const float erh = compf(er4, h);
        for (int e = start + g4; e < end; e += 4) {
            const unsigned int s = csr_src[e];
            const float av = __expf(leaky(el[s * 4 + h] + erh)) * rh;
            const float4 raw = *(const float4*)(feat + s * HD + gl * 8);
            const __half2* hp2 = (const __half2*)&raw;
            const float2 p0 = __half22float2(hp2[0]);
            const float2 p1 = __half22float2(hp2[1]);
            const float2 p2 = __half22float2(hp2[2]);
            const float2 p3 = __half22float2(hp2[3]);
            a0.x += av * p0.x; a0.y += av * p0.y;
            a0.z += av * p1.x; a0.w += av * p1.y;
            a1.x += av * p2.x; a1.y += av * p2.y;
            a1.z += av * p3.x; a1.w += av * p3.y;
        }
    }
#pragma unroll
    for (int off = 16; off <= 32; off <<= 1) {
        a0.x += __shfl_xor(a0.x, off);
        a0.y += __shfl_xor(a0.y, off);
        a0.z += __shfl_xor(a0.z, off);
        a0.w += __shfl_xor(a0.w, off);
        a1.x += __shfl_xor(a1.x, off);
        a1.y += __shfl_xor(a1.y, off);
        a1.z += __shfl_xor(a1.z, off);
        a1.w += __shfl_xor(a1.w, off);
    }
    if (lane < 16) {
        const float4 b0 = ((const float4*)gat_bias)[gl * 2];
        const float4 b1 = ((const float4*)gat_bias)[gl * 2 + 1];
        float4* hp = (float4*)(hn + (size_t)n * HD + gl * 8);
        hp[0] = make_float4(a0.x + b0.x, a0.y + b0.y, a0.z + b0.z, a0.w + b0.w);
        hp[1] = make_float4(a1.x + b1.x, a1.y + b1.y, a1.z + b1.z, a1.w + b1.w);
    }
}

// K6B: attention coefficients in edge order (2 gathers: el[s] + er_rd[d])
__global__ void __launch_bounds__(256) k6b_attn(
    const int* __restrict__ src, const int* __restrict__ dst,
    const float* __restrict__ el, const float* __restrict__ er_rd,
    float* __restrict__ a_out) {
    int e = blockIdx.x * 256 + threadIdx.x;
    if (e >= E_EDGES) return;
    const int s = src[e], d = dst[e];
    const float4 el4 = *(const float4*)(el + s * 4);
    const float4 er4 = *(const float4*)(er_rd + (size_t)d * 8);
    const float4 r4 = *(const float4*)(er_rd + (size_t)d * 8 + 4);
    vfloat4 a;
    a.x = __expf(leaky(el4.x + er4.x)) * r4.x;
    a.y = __expf(leaky(el4.y + er4.y)) * r4.y;
    a.z = __expf(leaky(el4.z + er4.z)) * r4.z;
    a.w = __expf(leaky(el4.w + er4.w)) * r4.w;
    __builtin_nontemporal_store(a, (vfloat4*)a_out + e);
}

// K7: deterministic f64 mean-pool + f64 MLP.
__global__ void __launch_bounds__(512) k7_pool_mlp(
    const float* __restrict__ hn, const int* __restrict__ graph_ids,
    const float* __restrict__ W1, const float* __restrict__ b1,
    const float* __restrict__ W2, const float* __restrict__ b2,
    const float* __restrict__ W3, const float* __restrict__ b3,
    float* __restrict__ out) {
    const int g = blockIdx.x, t = threadIdx.x;
    const int tt = t & 127, part = t >> 7;
    __shared__ int bounds[2];
    __shared__ double pool[4][128];
    __shared__ double x[128], y[128];
    if (t < 2) {
        const int target = g + t;
        int lo = 0, hi = N_NODES;
        while (lo < hi) {
            int mid = (lo + hi) >> 1;
            if (graph_ids[mid] < target) lo = mid + 1; else hi = mid;
        }
        bounds[t] = lo;
    }
    __syncthreads();
    const int lo = bounds[0], hi = bounds[1];
    double s = 0.0;
    for (int n = lo + part; n < hi; n += 4) s += (double)hn[(size_t)n * HD + tt];
    pool[part][tt] = s;
    __syncthreads();
    if (t < 128) {
        const double cnt = (double)(hi - lo);
        const double sum = pool[0][t] + pool[1][t] + pool[2][t] + pool[3][t];
        const double v = sum / fmax(cnt, 1.0);
        x[t] = v > 0.0 ? v : expm1(v);
    }
    __syncthreads();
    if (t < 128) {
        double acc = (double)b1[t];
        for (int k = 0; k < HD; ++k) acc += x[k] * (double)W1[k * D1 + t];
        y[t] = acc > 0.0 ? acc : expm1(acc);
    }
    __syncthreads();
    if (t < D2) {
        double a2 = (double)b2[t];
        for (int k = 0; k < D1; ++k) a2 += y[k] * (double)W2[k * D2 + t];
        x[t] = a2 > 0.0 ? a2 : expm1(a2);
    }
    __syncthreads();
    if (t < D3) {
        double a3 = (double)b3[t];
        for (int k = 0; k < D2; ++k) a3 += x[k] * (double)W3[k * D3 + t];
        out[g * D3 + t] = (float)a3;
    }
}

extern "C" void kernel_launch(void* const* d_in, const int* in_sizes, int n_in,
                              void* d_out, int out_size, void* d_ws, size_t ws_size,
                              hipStream_t stream) {
    const float* feature = (const float*)d_in[0];
    const int* src = (const int*)d_in[1];
    const int* dst = (const int*)d_in[2];
    const int* graph_ids = (const int*)d_in[3];
    const float* W0 = (const float*)d_in[4];
    const float* b0 = (const float*)d_in[5];
    const float* Wfc = (const float*)d_in[6];
    const float* attn_l = (const float*)d_in[7];
    const float* attn_r = (const float*)d_in[8];
    const float* gat_bias = (const float*)d_in[9];
    const float* W1 = (const float*)d_in[10];
    const float* b1 = (const float*)d_in[11];
    const float* W2 = (const float*)d_in[12];
    const float* b2 = (const float*)d_in[13];
    const float* W3 = (const float*)d_in[14];
    const float* b3 = (const float*)d_in[15];

    char* ws = (char*)d_ws;
    size_t off = 0;
    auto carve = [&](size_t bytes) -> void* {
        void* p = ws + off;
        off += (bytes + 255) & ~(size_t)255;
        return p;
    };
    int* ghist = (int*)carve((size_t)NB * 4);
    const size_t zero_span = off;
    int* coarse_start = (int*)carve((size_t)(NB + 1) * 4);
    int* cursorp = (int*)carve((size_t)NB * 4);
    float* Wc = (float*)carve((size_t)IN_DIM * HD * 4);
    float* bc = (float*)carve((size_t)HD * 4);
    __half* feat = (__half*)carve((size_t)N_NODES * HD * 2);
    float* el = (float*)carve((size_t)N_NODES * 4 * 4);
    float* er = (float*)carve((size_t)N_NODES * 4 * 4);
    float* er_rd = (float*)carve((size_t)N_NODES * 8 * 4);
    int* rowstart = (int*)carve((size_t)(N_NODES + 1) * 4);
    unsigned int* part = (unsigned int*)carve((size_t)E_EDGES * 4);
    ushort_t* csr_src = (ushort_t*)carve((size_t)E_EDGES * 2);

    float* out = (float*)d_out;
    // atten region of d_out doubles as hn scratch: k6 writes hn, k7 reads it,
    // THEN k6b overwrites the region with the final attention output.
    float* hn = out + G_GRAPHS * D3;
    float* a_out = hn;

    (void)hipMemsetAsync(d_ws, 0, zero_span, stream);
    k0hg<<<PT_BLOCKS + 33, 256, 0, stream>>>(dst, ghist, W0, b0, Wfc, Wc, bc);
    k1_gemm<<<(N_NODES + 31) / 32, 256, 0, stream>>>(feature, Wc, bc, attn_l, attn_r,
                                                     feat, el, er);
    sc_scan<<<1, 64, 0, stream>>>(ghist, coarse_start, cursorp);
    pt_partition<<<PT_BLOCKS, 256, 0, stream>>>(src, dst, cursorp, part);
    fb_fill<<<NB, 256, 0, stream>>>(part, coarse_start, rowstart, csr_src);
    k6_aggregate<<<(N_NODES + 3) / 4, 256, 0, stream>>>(csr_src, rowstart, el, er, feat,
                                                        gat_bias, er_rd, hn);
    k7_pool_mlp<<<G_GRAPHS, 512, 0, stream>>>(hn, graph_ids, W1, b1, W2, b2, W3, b3, out);
    k6b_attn<<<(E_EDGES + 255) / 256, 256, 0, stream>>>(src, dst, el, er_rd, a_out);
}

// Round 11
// 266.864 us; speedup vs baseline: 1.4169x; 1.1614x over previous
//
#include <hip/hip_runtime.h>
#include <hip/hip_fp16.h>
#include <math.h>

#define N_NODES 50000
#define E_EDGES 1600000
#define G_GRAPHS 512
#define IN_DIM 64
#define EMBED 128
#define HD 128
#define NHEAD 4
#define D1 128
#define D2 64
#define D3 16
#define NEG_SLOPE 0.2f
#define NB ((N_NODES + 127) >> 7)                       // 391 coarse buckets (128 nodes)
#define PT_TILE 4096
#define PT_BLOCKS ((E_EDGES + PT_TILE - 1) / PT_TILE)   // 391
#define FB_CAP 8192

typedef float vfloat4 __attribute__((ext_vector_type(4)));
typedef float vfloat2 __attribute__((ext_vector_type(2)));
typedef unsigned short ushort_t;

static __device__ __forceinline__ float leaky(float x) { return x > 0.f ? x : NEG_SLOPE * x; }
static __device__ __forceinline__ float compf(float4 v, int i) {
    return i == 0 ? v.x : (i == 1 ? v.y : (i == 2 ? v.z : v.w));
}

// K0+HG merged: blocks [0,PT_BLOCKS) do the coarse dst-histogram; the rest compute
// Wcomb = W0 @ Wfc and bcomb = b0 @ Wfc.
__global__ void __launch_bounds__(256) k0hg(const int* __restrict__ dst, int* __restrict__ ghist,
                                            const float* __restrict__ W0, const float* __restrict__ b0,
                                            const float* __restrict__ Wfc, float* __restrict__ Wc,
                                            float* __restrict__ bc) {
    __shared__ int lh[NB];
    const int t = threadIdx.x;
    if (blockIdx.x < PT_BLOCKS) {
        for (int i = t; i < NB; i += 256) lh[i] = 0;
        __syncthreads();
        const long e0 = (long)blockIdx.x * PT_TILE;
#pragma unroll
        for (int k = 0; k < PT_TILE / 256; ++k) {
            long e = e0 + t + k * 256;
            if (e < E_EDGES) atomicAdd(&lh[dst[e] >> 7], 1);
        }
        __syncthreads();
        for (int i = t; i < NB; i += 256) {
            int v = lh[i];
            if (v) atomicAdd(&ghist[i], v);
        }
    } else {
        int tid = (int)(blockIdx.x - PT_BLOCKS) * 256 + t;
        if (tid < IN_DIM * HD) {
            int i = tid >> 7, j = tid & 127;
            float acc = 0.f;
            for (int k = 0; k < EMBED; ++k) acc += W0[i * EMBED + k] * Wfc[k * HD + j];
            Wc[tid] = acc;
        } else if (tid < IN_DIM * HD + HD) {
            int j = tid - IN_DIM * HD;
            float acc = 0.f;
            for (int k = 0; k < EMBED; ++k) acc += b0[k] * Wfc[k * HD + j];
            bc[j] = acc;
        }
    }
}

// K1 (fused): feat = fp8_e4m3(feature @ Wc + bc) row-major; el/er epilogue from LDS tile.
// feat is ONLY consumed by k6 pass-2 (weighted message sum) whose error is averaged
// down by the graph pool -> fp8 is safe; el/er stay fp32 (computed from fs).
__global__ void __launch_bounds__(256) k1_gemm(const float* __restrict__ A,
                                               const float* __restrict__ W,
                                               const float* __restrict__ b,
                                               const float* __restrict__ attn_l,
                                               const float* __restrict__ attn_r,
                                               unsigned char* __restrict__ feat,
                                               float* __restrict__ el,
                                               float* __restrict__ er) {
    __shared__ float Ws[IN_DIM * HD];   // 32 KB
    __shared__ float As[32][65];        // 8.3 KB
    __shared__ float fs[32][132];       // 16.9 KB
    const int t = threadIdx.x;
    const int c = t & 127, rr = t >> 7;
    const int row0 = blockIdx.x * 32;
    for (int i = t; i < IN_DIM * HD; i += 256) Ws[i] = W[i];
    for (int i = t; i < 32 * IN_DIM; i += 256) {
        int r = i >> 6, k = i & 63;
        int gr = row0 + r;
        As[r][k] = (gr < N_NODES) ? A[(size_t)gr * IN_DIM + k] : 0.f;
    }
    __syncthreads();
    float acc[16];
#pragma unroll
    for (int i = 0; i < 16; ++i) acc[i] = 0.f;
    for (int k = 0; k < IN_DIM; ++k) {
        float w = Ws[k * HD + c];
#pragma unroll
        for (int i = 0; i < 16; ++i) acc[i] += As[rr * 16 + i][k] * w;
    }
    const float bb = b[c];
#pragma unroll
    for (int i = 0; i < 16; ++i) fs[rr * 16 + i][c] = acc[i] + bb;
    __syncthreads();
    // fp8 feat epilogue: unit = (row, 16-ch slice) -> 16 bytes, one 16B store
    {
        const int row = t >> 3, s = t & 7;
        const int gr = row0 + row;
        if (gr < N_NODES) {
            unsigned int w[4];
#pragma unroll
            for (int k = 0; k < 4; ++k) {
                unsigned int ww = __builtin_amdgcn_cvt_pk_fp8_f32(
                    fs[row][s * 16 + 4 * k], fs[row][s * 16 + 4 * k + 1], 0, false);
                ww = __builtin_amdgcn_cvt_pk_fp8_f32(
                    fs[row][s * 16 + 4 * k + 2], fs[row][s * 16 + 4 * k + 3], ww, true);
                w[k] = ww;
            }
            *(uint4*)(feat + (size_t)gr * HD + s * 16) = make_uint4(w[0], w[1], w[2], w[3]);
        }
    }
    // el/er epilogue: 8 threads per row, 16 channels each; pairs combine to one head.
    {
        const int r = t >> 3, q = t & 7, c0 = q * 16, h = q >> 1;
        float pl = 0.f, pr = 0.f;
#pragma unroll
        for (int k = 0; k < 16; ++k) {
            float f = fs[r][c0 + k];
            pl += f * attn_l[c0 + k];
            pr += f * attn_r[c0 + k];
        }
        pl += __shfl_xor(pl, 1);
        pr += __shfl_xor(pr, 1);
        if ((t & 1) == 0) {
            int n = row0 + r;
            if (n < N_NODES) {
                el[n * 4 + h] = pl;
                er[n * 4 + h] = pr;
            }
        }
    }
}

// SC: exclusive scan of NB coarse counts -> coarse_start + cursor (one wave)
__global__ void __launch_bounds__(64) sc_scan(const int* __restrict__ ghist,
                                              int* __restrict__ coarse_start,
                                              int* __restrict__ cursorp) {
    const int lane = threadIdx.x;
    int run = 0;
    for (int c = 0; c < (NB + 63) / 64; ++c) {
        int i = c * 64 + lane;
        int v = (i < NB) ? ghist[i] : 0;
        int incl = v;
#pragma unroll
        for (int off = 1; off < 64; off <<= 1) {
            int o = __shfl_up(incl, off, 64);
            if (lane >= off) incl += o;
        }
        if (i < NB) {
            coarse_start[i] = run + incl - v;
            cursorp[i] = run + incl - v;
        }
        run += __shfl(incl, 63, 64);
    }
    if (lane == 0) coarse_start[NB] = E_EDGES;
}

// PT: partition edges into coarse buckets; packed records (dst<<16)|src; per-wave hist.
__global__ void __launch_bounds__(256) pt_partition(const int* __restrict__ src,
                                                    const int* __restrict__ dst,
                                                    int* __restrict__ cursorp,
                                                    unsigned int* __restrict__ part) {
    __shared__ int hist[4][NB];
    __shared__ int tot[NB], offs[NB], base_s[NB];
    __shared__ int lcur[4][NB];
    __shared__ unsigned int stage[PT_TILE];  // 16 KB
    const int t = threadIdx.x, lane = t & 63, wid = t >> 6;
    const long e0 = (long)blockIdx.x * PT_TILE;
    const int cnt = (int)min((long)PT_TILE, (long)E_EDGES - e0);
    for (int i = t; i < NB; i += 256) {
        hist[0][i] = 0; hist[1][i] = 0; hist[2][i] = 0; hist[3][i] = 0;
    }
    __syncthreads();
    unsigned int v[PT_TILE / 256];
#pragma unroll
    for (int k = 0; k < PT_TILE / 256; ++k) {
        int i = t + k * 256;
        if (i < cnt) {
            int d = dst[e0 + i];
            v[k] = ((unsigned int)d << 16) | (unsigned int)src[e0 + i];
            atomicAdd(&hist[wid][d >> 7], 1);
        } else v[k] = 0xFFFFFFFFu;
    }
    __syncthreads();
    for (int i = t; i < NB; i += 256) {
        int h0 = hist[0][i], h1 = hist[1][i], h2 = hist[2][i], h3 = hist[3][i];
        hist[0][i] = 0; hist[1][i] = h0; hist[2][i] = h0 + h1; hist[3][i] = h0 + h1 + h2;
        tot[i] = h0 + h1 + h2 + h3;
    }
    __syncthreads();
    if (wid == 0) {
        int run = 0;
        for (int c = 0; c < (NB + 63) / 64; ++c) {
            int i = c * 64 + lane;
            int vv = (i < NB) ? tot[i] : 0;
            int incl = vv;
#pragma unroll
            for (int off = 1; off < 64; off <<= 1) {
                int o = __shfl_up(incl, off, 64);
                if (lane >= off) incl += o;
            }
            if (i < NB) offs[i] = run + incl - vv;
            run += __shfl(incl, 63, 64);
        }
    }
    __syncthreads();
    for (int i = t; i < NB; i += 256) {
        int tt = tot[i];
        base_s[i] = tt ? atomicAdd(&cursorp[i], tt) : 0;
        int ob = offs[i];
        lcur[0][i] = ob + hist[0][i];
        lcur[1][i] = ob + hist[1][i];
        lcur[2][i] = ob + hist[2][i];
        lcur[3][i] = ob + hist[3][i];
    }
    __syncthreads();
#pragma unroll
    for (int k = 0; k < PT_TILE / 256; ++k) {
        if (v[k] != 0xFFFFFFFFu) {
            int b = v[k] >> 23;
            int pos = atomicAdd(&lcur[wid][b], 1);
            stage[pos] = v[k];
        }
    }
    __syncthreads();
    for (int i = t; i < cnt; i += 256) {
        unsigned int p = stage[i];
        int b = p >> 23;
        part[base_s[b] + (i - offs[b])] = p & 0x7FFFFFu;  // (dst&127)<<16 | src
    }
}

// FB: per-bucket fine fill -> rowstart + coalesced ushort csr_src
__global__ void __launch_bounds__(256) fb_fill(const unsigned int* __restrict__ part,
                                               const int* __restrict__ coarse_start,
                                               int* __restrict__ rowstart,
                                               ushort_t* __restrict__ csr_src) {
    const int b = blockIdx.x, t = threadIdx.x, lane = t & 63, wid = t >> 6;
    const int s0 = coarse_start[b], s1 = coarse_start[b + 1];
    const int cnt = s1 - s0;
    __shared__ int degl[4][128], totl[128], offl[128], curl[4][128];
    __shared__ ushort_t lsrc[FB_CAP];  // 16 KB
    if (t < 128) { degl[0][t] = 0; degl[1][t] = 0; degl[2][t] = 0; degl[3][t] = 0; }
    __syncthreads();
    for (int i = t; i < cnt; i += 256) {
        unsigned int p = part[s0 + i];
        atomicAdd(&degl[wid][p >> 16], 1);
    }
    __syncthreads();
    if (t < 128) {
        int d0 = degl[0][t], d1 = degl[1][t], d2 = degl[2][t], d3 = degl[3][t];
        degl[0][t] = 0; degl[1][t] = d0; degl[2][t] = d0 + d1; degl[3][t] = d0 + d1 + d2;
        totl[t] = d0 + d1 + d2 + d3;
    }
    __syncthreads();
    if (wid == 0) {
        int run = 0;
        for (int c = 0; c < 2; ++c) {
            int i = c * 64 + lane;
            int vv = totl[i];
            int incl = vv;
#pragma unroll
            for (int off = 1; off < 64; off <<= 1) {
                int o = __shfl_up(incl, off, 64);
                if (lane >= off) incl += o;
            }
            offl[i] = run + incl - vv;
            run += __shfl(incl, 63, 64);
        }
    }
    __syncthreads();
    if (t < 128) {
        int ob = offl[t];
        curl[0][t] = ob + degl[0][t];
        curl[1][t] = ob + degl[1][t];
        curl[2][t] = ob + degl[2][t];
        curl[3][t] = ob + degl[3][t];
        int node = (b << 7) + t;
        if (node < N_NODES) rowstart[node] = s0 + ob;
    }
    if (b == 0 && t == 0) rowstart[N_NODES] = E_EDGES;
    __syncthreads();
    if (cnt <= FB_CAP) {
        for (int i = t; i < cnt; i += 256) {
            unsigned int p = part[s0 + i];
            int pos = atomicAdd(&curl[wid][p >> 16], 1);
            lsrc[pos] = (ushort_t)(p & 0xFFFFu);
        }
        __syncthreads();
        for (int i = t; i < cnt; i += 256) csr_src[s0 + i] = lsrc[i];
    } else {
        for (int i = t; i < cnt; i += 256) {
            unsigned int p = part[s0 + i];
            int pos = atomicAdd(&curl[wid][p >> 16], 1);
            csr_src[s0 + pos] = (ushort_t)(p & 0xFFFFu);
        }
    }
}

// K6: per-dst softmax (no-max form) + aggregation, fused. One wave per dst.
// Pass 1 stashes per-edge av[4]/src in LDS; writes er_rd = {er4, rd4} for k6b.
// Pass 2 gathers fp8 feat rows (128 B/edge).
__global__ void __launch_bounds__(256) k6_aggregate(
    const ushort_t* __restrict__ csr_src, const int* __restrict__ rowstart,
    const float* __restrict__ el, const float* __restrict__ er,
    const unsigned char* __restrict__ feat, const float* __restrict__ gat_bias,
    float* __restrict__ er_rd, float* __restrict__ hn) {
    __shared__ float s_av[4][64][4];  // [wave][edge][head], 4 KB
    __shared__ int s_src[4][64];      // 1 KB
    const int wid = threadIdx.x >> 6;
    const int lane = threadIdx.x & 63;
    const int n = blockIdx.x * 4 + wid;
    if (n >= N_NODES) return;
    const int start = rowstart[n];
    const int end = rowstart[n + 1];
    const int deg = end - start;
    const float4 er4 = *(const float4*)(er + n * 4);

    // ---- pass 1: exp + sum (no max needed: |e| small so exp is safe) ----
    int esrc = 0;
    float4 ex = make_float4(0.f, 0.f, 0.f, 0.f);
    const bool valid = lane < deg;
    if (valid) {
        esrc = csr_src[start + lane];
        const float4 elv = *(const float4*)(el + esrc * 4);
        ex.x = __expf(leaky(elv.x + er4.x));
        ex.y = __expf(leaky(elv.y + er4.y));
        ex.z = __expf(leaky(elv.z + er4.z));
        ex.w = __expf(leaky(elv.w + er4.w));
    }
    float4 sm = ex;
    for (int e = start + lane + 64; e < end; e += 64) {  // deg>64: essentially never
        int s = csr_src[e];
        const float4 elv = *(const float4*)(el + s * 4);
        sm.x += __expf(leaky(elv.x + er4.x));
        sm.y += __expf(leaky(elv.y + er4.y));
        sm.z += __expf(leaky(elv.z + er4.z));
        sm.w += __expf(leaky(elv.w + er4.w));
    }
#pragma unroll
    for (int off = 32; off; off >>= 1) {
        sm.x += __shfl_xor(sm.x, off);
        sm.y += __shfl_xor(sm.y, off);
        sm.z += __shfl_xor(sm.z, off);
        sm.w += __shfl_xor(sm.w, off);
    }
    float4 rd;
    rd.x = sm.x > 0.f ? 1.f / sm.x : 0.f;
    rd.y = sm.y > 0.f ? 1.f / sm.y : 0.f;
    rd.z = sm.z > 0.f ? 1.f / sm.z : 0.f;
    rd.w = sm.w > 0.f ? 1.f / sm.w : 0.f;
    if (lane == 0) {
        *(float4*)(er_rd + (size_t)n * 8) = er4;
        *(float4*)(er_rd + (size_t)n * 8 + 4) = rd;
    }
    vfloat4 av4;
    av4.x = ex.x * rd.x;
    av4.y = ex.y * rd.y;
    av4.z = ex.z * rd.z;
    av4.w = ex.w * rd.w;
    s_src[wid][lane] = valid ? esrc : 0;
    *(vfloat4*)(&s_av[wid][lane][0]) = av4;

    // ---- pass 2: 16 lanes per edge (8B fp8 each = 8 channels, one head per lane) ----
    const int g4 = lane >> 4, gl = lane & 15;
    const int h = gl >> 2;
    float4 a0 = make_float4(0.f, 0.f, 0.f, 0.f);
    float4 a1 = make_float4(0.f, 0.f, 0.f, 0.f);

    if (deg <= 64) {
        const int iters = (deg + 3) >> 2;
        int idx = g4;
        for (int it = 0; it < iters; ++it, idx += 4) {
            const float av = s_av[wid][idx][h];
            const unsigned int cs = (unsigned int)s_src[wid][idx];
            const uint2 w = *(const uint2*)(feat + (size_t)cs * HD + gl * 8);
            const vfloat2 p0 = __builtin_amdgcn_cvt_pk_f32_fp8(w.x, false);
            const vfloat2 p1 = __builtin_amdgcn_cvt_pk_f32_fp8(w.x, true);
            const vfloat2 p2 = __builtin_amdgcn_cvt_pk_f32_fp8(w.y, false);
            const vfloat2 p3 = __builtin_amdgcn_cvt_pk_f32_fp8(w.y, true);
            a0.x += av * p0.x; a0.y += av * p0.y;
            a0.z += av * p1.x; a0.w += av * p1.y;
            a1.x += av * p2.x; a1.y += av * p2.y;
            a1.z += av * p3.x; a1.w += av * p3.y;
        }
    } else {
        const float rh = compf(rd, h);
        const float erh = compf(er4, h);
        for (int e = start + g4; e < end; e += 4) {
            const unsigned int s = csr_src[e];
            const float av = __expf(leaky(el[s * 4 + h] + erh)) * rh;
            const uint2 w = *(const uint2*)(feat + (size_t)s * HD + gl * 8);
            const vfloat2 p0 = __builtin_amdgcn_cvt_pk_f32_fp8(w.x, false);
            const vfloat2 p1 = __builtin_amdgcn_cvt_pk_f32_fp8(w.x, true);
            const vfloat2 p2 = __builtin_amdgcn_cvt_pk_f32_fp8(w.y, false);
            const vfloat2 p3 = __builtin_amdgcn_cvt_pk_f32_fp8(w.y, true);
            a0.x += av * p0.x; a0.y += av * p0.y;
            a0.z += av * p1.x; a0.w += av * p1.y;
            a1.x += av * p2.x; a1.y += av * p2.y;
            a1.z += av * p3.x; a1.w += av * p3.y;
        }
    }
#pragma unroll
    for (int off = 16; off <= 32; off <<= 1) {
        a0.x += __shfl_xor(a0.x, off);
        a0.y += __shfl_xor(a0.y, off);
        a0.z += __shfl_xor(a0.z, off);
        a0.w += __shfl_xor(a0.w, off);
        a1.x += __shfl_xor(a1.x, off);
        a1.y += __shfl_xor(a1.y, off);
        a1.z += __shfl_xor(a1.z, off);
        a1.w += __shfl_xor(a1.w, off);
    }
    if (lane < 16) {
        const float4 b0 = ((const float4*)gat_bias)[gl * 2];
        const float4 b1 = ((const float4*)gat_bias)[gl * 2 + 1];
        float4* hp = (float4*)(hn + (size_t)n * HD + gl * 8);
        hp[0] = make_float4(a0.x + b0.x, a0.y + b0.y, a0.z + b0.z, a0.w + b0.w);
        hp[1] = make_float4(a1.x + b1.x, a1.y + b1.y, a1.z + b1.z, a1.w + b1.w);
    }
}

// K6B: attention coefficients in edge order (2 gathers: el[s] + er_rd[d])
__global__ void __launch_bounds__(256) k6b_attn(
    const int* __restrict__ src, const int* __restrict__ dst,
    const float* __restrict__ el, const float* __restrict__ er_rd,
    float* __restrict__ a_out) {
    int e = blockIdx.x * 256 + threadIdx.x;
    if (e >= E_EDGES) return;
    const int s = src[e], d = dst[e];
    const float4 el4 = *(const float4*)(el + s * 4);
    const float4 er4 = *(const float4*)(er_rd + (size_t)d * 8);
    const float4 r4 = *(const float4*)(er_rd + (size_t)d * 8 + 4);
    vfloat4 a;
    a.x = __expf(leaky(el4.x + er4.x)) * r4.x;
    a.y = __expf(leaky(el4.y + er4.y)) * r4.y;
    a.z = __expf(leaky(el4.z + er4.z)) * r4.z;
    a.w = __expf(leaky(el4.w + er4.w)) * r4.w;
    __builtin_nontemporal_store(a, (vfloat4*)a_out + e);
}

// K7: deterministic f64 mean-pool + f64 MLP.
__global__ void __launch_bounds__(512) k7_pool_mlp(
    const float* __restrict__ hn, const int* __restrict__ graph_ids,
    const float* __restrict__ W1, const float* __restrict__ b1,
    const float* __restrict__ W2, const float* __restrict__ b2,
    const float* __restrict__ W3, const float* __restrict__ b3,
    float* __restrict__ out) {
    const int g = blockIdx.x, t = threadIdx.x;
    const int tt = t & 127, part = t >> 7;
    __shared__ int bounds[2];
    __shared__ double pool[4][128];
    __shared__ double x[128], y[128];
    if (t < 2) {
        const int target = g + t;
        int lo = 0, hi = N_NODES;
        while (lo < hi) {
            int mid = (lo + hi) >> 1;
            if (graph_ids[mid] < target) lo = mid + 1; else hi = mid;
        }
        bounds[t] = lo;
    }
    __syncthreads();
    const int lo = bounds[0], hi = bounds[1];
    double s = 0.0;
    for (int n = lo + part; n < hi; n += 4) s += (double)hn[(size_t)n * HD + tt];
    pool[part][tt] = s;
    __syncthreads();
    if (t < 128) {
        const double cnt = (double)(hi - lo);
        const double sum = pool[0][t] + pool[1][t] + pool[2][t] + pool[3][t];
        const double v = sum / fmax(cnt, 1.0);
        x[t] = v > 0.0 ? v : expm1(v);
    }
    __syncthreads();
    if (t < 128) {
        double acc = (double)b1[t];
        for (int k = 0; k < HD; ++k) acc += x[k] * (double)W1[k * D1 + t];
        y[t] = acc > 0.0 ? acc : expm1(acc);
    }
    __syncthreads();
    if (t < D2) {
        double a2 = (double)b2[t];
        for (int k = 0; k < D1; ++k) a2 += y[k] * (double)W2[k * D2 + t];
        x[t] = a2 > 0.0 ? a2 : expm1(a2);
    }
    __syncthreads();
    if (t < D3) {
        double a3 = (double)b3[t];
        for (int k = 0; k < D2; ++k) a3 += x[k] * (double)W3[k * D3 + t];
        out[g * D3 + t] = (float)a3;
    }
}

extern "C" void kernel_launch(void* const* d_in, const int* in_sizes, int n_in,
                              void* d_out, int out_size, void* d_ws, size_t ws_size,
                              hipStream_t stream) {
    const float* feature = (const float*)d_in[0];
    const int* src = (const int*)d_in[1];
    const int* dst = (const int*)d_in[2];
    const int* graph_ids = (const int*)d_in[3];
    const float* W0 = (const float*)d_in[4];
    const float* b0 = (const float*)d_in[5];
    const float* Wfc = (const float*)d_in[6];
    const float* attn_l = (const float*)d_in[7];
    const float* attn_r = (const float*)d_in[8];
    const float* gat_bias = (const float*)d_in[9];
    const float* W1 = (const float*)d_in[10];
    const float* b1 = (const float*)d_in[11];
    const float* W2 = (const float*)d_in[12];
    const float* b2 = (const float*)d_in[13];
    const float* W3 = (const float*)d_in[14];
    const float* b3 = (const float*)d_in[15];

    char* ws = (char*)d_ws;
    size_t off = 0;
    auto carve = [&](size_t bytes) -> void* {
        void* p = ws + off;
        off += (bytes + 255) & ~(size_t)255;
        return p;
    };
    int* ghist = (int*)carve((size_t)NB * 4);
    const size_t zero_span = off;
    int* coarse_start = (int*)carve((size_t)(NB + 1) * 4);
    int* cursorp = (int*)carve((size_t)NB * 4);
    float* Wc = (float*)carve((size_t)IN_DIM * HD * 4);
    float* bc = (float*)carve((size_t)HD * 4);
    unsigned char* feat = (unsigned char*)carve((size_t)N_NODES * HD);
    float* el = (float*)carve((size_t)N_NODES * 4 * 4);
    float* er = (float*)carve((size_t)N_NODES * 4 * 4);
    float* er_rd = (float*)carve((size_t)N_NODES * 8 * 4);
    int* rowstart = (int*)carve((size_t)(N_NODES + 1) * 4);
    unsigned int* part = (unsigned int*)carve((size_t)E_EDGES * 4);
    ushort_t* csr_src = (ushort_t*)carve((size_t)E_EDGES * 2);

    float* out = (float*)d_out;
    // atten region of d_out doubles as hn scratch: k6 writes hn, k7 reads it,
    // THEN k6b overwrites the region with the final attention output.
    float* hn = out + G_GRAPHS * D3;
    float* a_out = hn;

    (void)hipMemsetAsync(d_ws, 0, zero_span, stream);
    k0hg<<<PT_BLOCKS + 33, 256, 0, stream>>>(dst, ghist, W0, b0, Wfc, Wc, bc);
    k1_gemm<<<(N_NODES + 31) / 32, 256, 0, stream>>>(feature, Wc, bc, attn_l, attn_r,
                                                     feat, el, er);
    sc_scan<<<1, 64, 0, stream>>>(ghist, coarse_start, cursorp);
    pt_partition<<<PT_BLOCKS, 256, 0, stream>>>(src, dst, cursorp, part);
    fb_fill<<<NB, 256, 0, stream>>>(part, coarse_start, rowstart, csr_src);
    k6_aggregate<<<(N_NODES + 3) / 4, 256, 0, stream>>>(csr_src, rowstart, el, er, feat,
                                                        gat_bias, er_rd, hn);
    k7_pool_mlp<<<G_GRAPHS, 512, 0, stream>>>(hn, graph_ids, W1, b1, W2, b2, W3, b3, out);
    k6b_attn<<<(E_EDGES + 255) / 256, 256, 0, stream>>>(src, dst, el, er_rd, a_out);
}